// Round 15
// baseline (277.755 us; speedup 1.0000x reference)
//
#include <hip/hip_runtime.h>
#include <hip/hip_bf16.h>
#include <math.h>

#define BB 4
#define CC 256
#define HH 128
#define WW 128
#define HWS (HH*WW)          // 16384
#define NHEADS 8
#define DD (HWS/NHEADS)      // 2048

typedef __attribute__((ext_vector_type(8))) short bf16x8;
typedef __attribute__((ext_vector_type(4))) float f32x4;
typedef __attribute__((ext_vector_type(2))) __fp16 h16x2;
typedef __attribute__((ext_vector_type(8))) __fp16 h16x8;

#define GLD_LDS(g, l) __builtin_amdgcn_global_load_lds( \
    (const __attribute__((address_space(1))) void*)(g),  \
    (__attribute__((address_space(3))) void*)(l), 16, 0, 0)

static __device__ __forceinline__ unsigned short f2bf(float f) {
    unsigned int u = __float_as_uint(f);
    unsigned int r = (u + 0x7FFFu + ((u >> 16) & 1u)) >> 16;
    return (unsigned short)r;
}
static __device__ __forceinline__ float b2f(unsigned short u) {
    return __uint_as_float((unsigned int)u << 16);
}
static __device__ __forceinline__ unsigned int pk2(float a, float b) {
    union { h16x2 h; unsigned int u; } x;
    x.h = __builtin_amdgcn_cvt_pkrtz(a, b);
    return x.u;
}

// ---- Toeplitz fragment tables for MFMA conv: wt[c][cv][ky][lane][8] f16 ----
// T[m][k] = w[c][ky][k-m] for 0<=k-m<=8 else 0; lane: m=lane&15, k=(lane>>4)*8+e
__global__ __launch_bounds__(256) void build_wt(
    const float* __restrict__ qw, const float* __restrict__ kw,
    const float* __restrict__ vw, unsigned short* __restrict__ wt)
{
    const int c = blockIdx.x, cv = blockIdx.y;
    const float* w = (cv == 0) ? qw : (cv == 1) ? kw : vw;
    unsigned short* dst = wt + ((size_t)c * 3 + cv) * 9 * 512;
    for (int idx = threadIdx.x; idx < 9 * 512; idx += 256) {
        const int ky   = idx >> 9;
        const int rem  = idx & 511;
        const int lane = rem >> 3, e = rem & 7;
        const int m = lane & 15;
        const int k = ((lane >> 4) << 3) + e;
        const int d = k - m;
        const float v = (d >= 0 && d <= 8) ? w[c * 81 + ky * 9 + d] : 0.0f;
        const __fp16 hv = (__fp16)v;
        unsigned short bits;
        __builtin_memcpy(&bits, &hv, 2);
        dst[idx] = bits;
    }
}

// ------- fused QKV depthwise 9x9 conv — MFMA Toeplitz, 128x128 full-row tiles -------
// 1024 thr / 16 waves (8 wy x 2 wx); grid 1024 = 256c x 4batch (XCD-chunked).
// Tile 136 rows x 144 f16 cols (288B stride; same swizzle/bank math as the
// proven 160B version: both strides = 2x16 mod 128). Max read byte 39152 <
// 39168 staged -> no unwritten-LDS overhang. LDS 66816 -> 2 blocks/CU = 32 waves.
#define FOFF 27648
#define PE_COEF   (-1.1243088e-3f) // -ln(10000)/8192
#define PE_RSTEP  (0.99887632f)    // exp(PE_COEF)
__global__ __launch_bounds__(1024, 8) void conv9qkv(
    const float* __restrict__ in,
    const unsigned short* __restrict__ wt,
    const float* __restrict__ b0, const float* __restrict__ b1,
    const float* __restrict__ b2,
    unsigned short* __restrict__ o0, unsigned short* __restrict__ o1,
    unsigned short* __restrict__ o2)
{
    __shared__ alignas(16) char lds[FOFF + 39168];   // 66816 B

    const int u    = ((blockIdx.x & 7) << 7) + (blockIdx.x >> 3);
    const int c    = u >> 2;
    const int bidx = u & 3;
    const int tid  = threadIdx.x;
    const int lane = tid & 63;
    const int wr   = tid >> 6;       // 0..15
    const int wy   = wr >> 1;        // 0..7
    const int wx   = wr & 1;         // 0..1
    const int r16  = lane & 15;
    const int g    = lane >> 4;

    // ---- async staging of the 27 Toeplitz fragments ----
    for (int f = wr; f < 27; f += 16) {
        const char* src = (const char*)wt + (((size_t)c * 27 + f) << 10) + (lane << 4);
        GLD_LDS(src, lds + (f << 10) + (lane << 4));
    }

    const float* xp = in + ((size_t)(bidx * CC + c) << 14);
    const float cf  = (float)c;

    // ---- stage 136x144 halo tile (x + inline PE) as f16, 288B stride, 8 px/item ----
    #pragma unroll
    for (int it = 0; it < 3; ++it) {
        const int i = tid + (it << 10);
        if (i < 2448) {
            const int row = i / 18;
            const int c8  = i - row * 18;
            const int gy  = row - 4;
            const int gx  = (c8 << 3) - 4;
            uint4 wv = make_uint4(0u, 0u, 0u, 0u);
            if (gy >= 0 && gy < HH) {
                const float* xr = xp + (gy << 7);
                if (gx >= 0 && gx + 7 < WW) {
                    const float4 a0 = *(const float4*)(xr + gx);
                    const float4 a1 = *(const float4*)(xr + gx + 4);
                    float dt = __expf(PE_COEF * (float)(((gy << 7) + gx) >> 1));
                    float s, cc;
                    __sincosf(cf * dt, &s, &cc);
                    wv.x = pk2(a0.x + s, a0.y + cc);
                    dt *= PE_RSTEP;
                    __sincosf(cf * dt, &s, &cc);
                    wv.y = pk2(a0.z + s, a0.w + cc);
                    dt *= PE_RSTEP;
                    __sincosf(cf * dt, &s, &cc);
                    wv.z = pk2(a1.x + s, a1.y + cc);
                    dt *= PE_RSTEP;
                    __sincosf(cf * dt, &s, &cc);
                    wv.w = pk2(a1.z + s, a1.w + cc);
                } else {
                    float vv[8];
                    #pragma unroll
                    for (int e = 0; e < 8; ++e) {
                        const int gxe = gx + e;
                        float xv = 0.f;
                        if (gxe >= 0 && gxe < WW) {
                            const int flat = (gy << 7) + gxe;
                            const float dt = __expf(PE_COEF * (float)(flat >> 1));
                            float s, cc;
                            __sincosf(cf * dt, &s, &cc);
                            xv = xr[gxe] + ((flat & 1) ? cc : s);
                        }
                        vv[e] = xv;
                    }
                    wv.x = pk2(vv[0], vv[1]); wv.y = pk2(vv[2], vv[3]);
                    wv.z = pk2(vv[4], vv[5]); wv.w = pk2(vv[6], vv[7]);
                }
            }
            int byte = row * 288 + (c8 << 4);
            byte ^= (row & 7) << 4;
            *(uint4*)(lds + FOFF + byte) = wv;
        }
    }
    __syncthreads();

    // ---- MFMA main: D[m=x][n=y] += T[m][k=x'] * In[k=x'][n=y], per ky ----
    f32x4 acc[3][4];
    {
        const float bq = b0[c], bk = b1[c], bv = b2[c];
        #pragma unroll
        for (int xt = 0; xt < 4; ++xt) {
            acc[0][xt] = (f32x4){bq, bq, bq, bq};
            acc[1][xt] = (f32x4){bk, bk, bk, bk};
            acc[2][xt] = (f32x4){bv, bv, bv, bv};
        }
    }

    const int rowbase = (wy << 4) + r16;     // output row 0..127
    const int xoff    = wx << 7;             // 0 or 128 bytes (64 cols)
    __builtin_amdgcn_s_setprio(1);
    for (int ky = 0; ky < 9; ++ky) {
        const int row = rowbase + ky;
        const int sx  = (row & 7) << 4;
        const int rb  = row * 288 + xoff + (g << 4);
        h16x8 a[4];
        #pragma unroll
        for (int xt = 0; xt < 4; ++xt)
            a[xt] = *(const h16x8*)(lds + FOFF + ((rb + (xt << 5)) ^ sx));
        #pragma unroll
        for (int cv = 0; cv < 3; ++cv) {
            const h16x8 tf = *(const h16x8*)(lds + ((cv * 9 + ky) << 10) + (lane << 4));
            #pragma unroll
            for (int xt = 0; xt < 4; ++xt)
                acc[cv][xt] = __builtin_amdgcn_mfma_f32_16x16x32_f16(
                    tf, a[xt], acc[cv][xt], 0, 0, 0);
        }
    }
    __builtin_amdgcn_s_setprio(0);

    // ---- epilogue: direct packed stores (lane holds 4 consecutive x at row y) ----
    unsigned short* const outs[3] = { o0, o1, o2 };
    const size_t base = (((size_t)(bidx * NHEADS + wy) * CC + c) << 11)
                      + ((size_t)r16 << 7) + (wx << 6) + (g << 2);
    #pragma unroll
    for (int cv = 0; cv < 3; ++cv)
        #pragma unroll
        for (int xt = 0; xt < 4; ++xt) {
            ushort4 uo;
            uo.x = f2bf(acc[cv][xt][0]); uo.y = f2bf(acc[cv][xt][1]);
            uo.z = f2bf(acc[cv][xt][2]); uo.w = f2bf(acc[cv][xt][3]);
            *(ushort4*)(outs[cv] + base + (xt << 4)) = uo;
        }
}

// ------- output depthwise 9x9 conv — 512-thr full-height tiles (byte-identical r12) -------
#define OTILE 21760
__global__ __launch_bounds__(512, 8) void conv9o(
    const unsigned short* __restrict__ ain,
    const float* __restrict__ w, const float* __restrict__ b,
    float* __restrict__ out)
{
    __shared__ alignas(16) char lds[OTILE + 9216];
    __shared__ float lw[81];

    const int u    = ((blockIdx.x & 7) << 8) + (blockIdx.x >> 3);
    const int c    = u >> 3;
    const int bidx = (u >> 1) & 3;
    const int tc   = (u & 1) << 6;
    const int plane = bidx * CC + c;
    const int tid  = threadIdx.x;
    const int lane = tid & 63;
    const int wr   = tid >> 6;
    const int r16  = lane & 15;
    const int g    = lane >> 4;

    if (tid < 81) lw[tid] = w[c * 81 + tid];

    const unsigned short* ap = ain + ((size_t)plane << 14);

    #pragma unroll
    for (int it = 0; it < 3; ++it) {
        const int i = tid + (it << 9);
        if (i < 1360) {
            const int row = i / 10;
            const int c8  = i - row * 10;
            const int gy  = row - 4;
            const int gx  = tc + (c8 << 3) - 4;
            uint4 wv = make_uint4(0u, 0u, 0u, 0u);
            if (gy >= 0 && gy < HH) {
                const unsigned short* ar = ap + (gy << 7);
                if (gx >= 0 && gx + 7 < WW) {
                    const bf16x8 uu = *(const bf16x8*)(ar + gx);
                    wv.x = pk2(b2f((unsigned short)uu[0]), b2f((unsigned short)uu[1]));
                    wv.y = pk2(b2f((unsigned short)uu[2]), b2f((unsigned short)uu[3]));
                    wv.z = pk2(b2f((unsigned short)uu[4]), b2f((unsigned short)uu[5]));
                    wv.w = pk2(b2f((unsigned short)uu[6]), b2f((unsigned short)uu[7]));
                } else {
                    float vv[8];
                    #pragma unroll
                    for (int e = 0; e < 8; ++e) {
                        const int gxe = gx + e;
                        vv[e] = (gxe >= 0 && gxe < WW) ? b2f(ar[gxe]) : 0.f;
                    }
                    wv.x = pk2(vv[0], vv[1]); wv.y = pk2(vv[2], vv[3]);
                    wv.z = pk2(vv[4], vv[5]); wv.w = pk2(vv[6], vv[7]);
                }
            }
            int byte = row * 160 + (c8 << 4);
            byte ^= (row & 7) << 4;
            *(uint4*)(lds + byte) = wv;
        }
    }
    __syncthreads();

    if (tid < 256) {
        const int ln = tid >> 2, qq = tid & 3;
        const int m  = ln & 15;
        const int k0 = ((ln >> 4) << 3) + (qq << 1);
        const int d0 = k0 - m, d1 = k0 + 1 - m;
        #pragma unroll
        for (int ky = 0; ky < 9; ++ky) {
            const float f0 = (d0 >= 0 && d0 <= 8) ? lw[ky * 9 + d0] : 0.f;
            const float f1 = (d1 >= 0 && d1 <= 8) ? lw[ky * 9 + d1] : 0.f;
            *(unsigned int*)(lds + OTILE + (ky << 10) + (ln << 4) + (qq << 2)) = pk2(f0, f1);
        }
    }
    __syncthreads();

    const float bv = b[c];
    f32x4 acc[4];
    #pragma unroll
    for (int xt = 0; xt < 4; ++xt) acc[xt] = (f32x4){bv, bv, bv, bv};

    const int rowbase = (wr << 4) + r16;
    __builtin_amdgcn_s_setprio(1);
    for (int ky = 0; ky < 9; ++ky) {
        const int row = rowbase + ky;
        const int sx  = (row & 7) << 4;
        const int rb  = row * 160 + (g << 4);
        h16x8 a[4];
        #pragma unroll
        for (int xt = 0; xt < 4; ++xt)
            a[xt] = *(const h16x8*)(lds + ((rb + (xt << 5)) ^ sx));
        const h16x8 tf = *(const h16x8*)(lds + OTILE + (ky << 10) + (lane << 4));
        #pragma unroll
        for (int xt = 0; xt < 4; ++xt)
            acc[xt] = __builtin_amdgcn_mfma_f32_16x16x32_f16(tf, a[xt], acc[xt], 0, 0, 0);
    }
    __builtin_amdgcn_s_setprio(0);

    const int y = (wr << 4) + r16;
    float* orow = out + ((size_t)plane << 14) + ((size_t)y << 7) + tc + (g << 2);
    #pragma unroll
    for (int xt = 0; xt < 4; ++xt)
        *(f32x4*)(orow + (xt << 4)) = acc[xt];
}

// ------------- bf16 MFMA GEMM for QK^T — double-buffered, 64x64 tiles (r12) -------------
__global__ __launch_bounds__(256) void gemm_qk(
    const unsigned short* __restrict__ Abuf, const unsigned short* __restrict__ Bbuf,
    float* __restrict__ Sout)
{
    constexpr int KT = 2048;

    __shared__ char lds[32768];   // two halves of 16KB: A 8KB + B 8KB each

    const int tid = threadIdx.x;
    const int bh  = blockIdx.z;
    const int m0  = blockIdx.y << 6;
    const int n0  = blockIdx.x << 6;

    const unsigned short* Ab = Abuf + (size_t)bh * CC * KT + (size_t)m0 * KT;
    const unsigned short* Bb = Bbuf + (size_t)bh * CC * KT + (size_t)n0 * KT;

    const int lane = tid & 63;
    const int w    = tid >> 6;       // 4 waves: 2m x 2n
    const int wm   = (w >> 1) << 5;
    const int wn   = (w & 1) << 5;
    const int r16  = lane & 15;
    const int g    = lane >> 4;

    const int trow = tid >> 3;       // 0..31
    const int slot = tid & 7;

    f32x4 acc[2][2] = {};

    auto stage = [&](int h, int kt) {
        const int kc = kt << 6;
        char* base = lds + h * 16384;
        #pragma unroll
        for (int i = 0; i < 2; ++i) {
            const int row = (i << 5) + trow;
            const int gs  = slot ^ (row & 7);
            GLD_LDS((const char*)(Ab + (size_t)row * KT + kc) + gs * 16,
                    base + (i << 12) + tid * 16);
        }
        #pragma unroll
        for (int i = 0; i < 2; ++i) {
            const int row = (i << 5) + trow;
            const int gs  = slot ^ (row & 7);
            GLD_LDS((const char*)(Bb + (size_t)row * KT + kc) + gs * 16,
                    base + 8192 + (i << 12) + tid * 16);
        }
    };

    stage(0, 0);
    __syncthreads();

    for (int kt = 0; kt < KT / 64; ++kt) {
        const int cur = kt & 1;
        if (kt + 1 < KT / 64) stage(cur ^ 1, kt + 1);
        const char* hb = lds + cur * 16384;
        #pragma unroll
        for (int kk = 0; kk < 2; ++kk) {
            bf16x8 af[2], bfr[2];
            #pragma unroll
            for (int mi = 0; mi < 2; ++mi) {
                const int row = wm + (mi << 4) + r16;
                af[mi] = *(const bf16x8*)(hb + row * 128 + ((((kk << 2) + g) ^ (row & 7)) << 4));
            }
            #pragma unroll
            for (int nj = 0; nj < 2; ++nj) {
                const int row = wn + (nj << 4) + r16;
                bfr[nj] = *(const bf16x8*)(hb + 8192 + row * 128 + ((((kk << 2) + g) ^ (row & 7)) << 4));
            }
            #pragma unroll
            for (int mi = 0; mi < 2; ++mi)
                #pragma unroll
                for (int nj = 0; nj < 2; ++nj)
                    acc[mi][nj] = __builtin_amdgcn_mfma_f32_16x16x32_bf16(af[mi], bfr[nj], acc[mi][nj], 0, 0, 0);
        }
        __syncthreads();
    }

    float* sp = Sout + (size_t)bh * 65536;
    #pragma unroll
    for (int mi = 0; mi < 2; ++mi)
        #pragma unroll
        for (int nj = 0; nj < 2; ++nj)
            #pragma unroll
            for (int j = 0; j < 4; ++j) {
                const int row = m0 + wm + (mi << 4) + (g << 2) + j;
                const int col = n0 + wn + (nj << 4) + r16;
                sp[(size_t)row * 256 + col] = acc[mi][nj][j] * 0.0078125f;
            }
}

// ------------- row softmax, wave-per-row (byte-identical r8) -------------
__global__ __launch_bounds__(256) void softmax_kernel(
    const float* __restrict__ S, unsigned short* __restrict__ P)
{
    const int row  = (blockIdx.x << 2) + (threadIdx.x >> 6);
    const int lane = threadIdx.x & 63;
    const float4 vv = *(const float4*)(S + ((size_t)row << 8) + (lane << 2));
    float m = fmaxf(fmaxf(vv.x, vv.y), fmaxf(vv.z, vv.w));
    #pragma unroll
    for (int o = 32; o; o >>= 1) m = fmaxf(m, __shfl_xor(m, o, 64));
    const float e0 = __expf(vv.x - m), e1 = __expf(vv.y - m);
    const float e2 = __expf(vv.z - m), e3 = __expf(vv.w - m);
    float s = (e0 + e1) + (e2 + e3);
    #pragma unroll
    for (int o = 32; o; o >>= 1) s += __shfl_xor(s, o, 64);
    const float r = 1.0f / s;
    ushort4 u;
    u.x = f2bf(e0 * r); u.y = f2bf(e1 * r); u.z = f2bf(e2 * r); u.w = f2bf(e3 * r);
    *(ushort4*)(P + ((size_t)row << 8) + (lane << 2)) = u;
}

// ------------- PV GEMM with fused V-transpose (byte-identical r12, 128-row tiles) -------------
__global__ __launch_bounds__(256) void gemm_pv(
    const unsigned short* __restrict__ Pbuf, const unsigned short* __restrict__ vbuf,
    unsigned short* __restrict__ Ao)
{
    __shared__ alignas(16) char lds[49152];

    const int tid = threadIdx.x;
    const int bh  = blockIdx.z;
    const int m0  = blockIdx.y << 7;
    const int n0  = blockIdx.x << 6;

    const unsigned short* Ab = Pbuf + ((size_t)bh << 16) + ((size_t)m0 << 8);

    const int lane = tid & 63;
    const int w    = tid >> 6;
    const int wm   = (w >> 1) << 6;
    const int wn   = (w & 1) << 5;
    const int r16  = lane & 15;
    const int g    = lane >> 4;
    const int trow = tid >> 3;
    const int slot = tid & 7;

    {
        #pragma unroll
        for (int i = 0; i < 4; ++i) {
            const int row = (i << 5) + trow;
            const int gs  = slot ^ (row & 7);
            GLD_LDS((const char*)(Ab + (size_t)row * 256) + gs * 16,
                    lds + (i << 12) + tid * 16);
        }
    }

    {
        const unsigned short* Vb = vbuf + (size_t)bh * (CC * DD) + n0;
        const int rl = tid >> 2, q4 = tid & 3;
        #pragma unroll
        for (int p = 0; p < 4; ++p) {
            const int cp = (p << 6) + rl;
            const unsigned short* src = Vb + (size_t)cp * DD + (q4 << 4);
            const bf16x8 v0 = *(const bf16x8*)(src);
            const bf16x8 v1 = *(const bf16x8*)(src + 8);
            const int cb = cp << 1;
            #pragma unroll
            for (int e = 0; e < 8; ++e) {
                const int d0 = (q4 << 4) + e, d1 = d0 + 8;
                *(unsigned short*)(lds + 16384 + d0 * 512 +
                    (cb ^ (((d0 & 7) ^ (d0 >> 3)) << 4))) = (unsigned short)v0[e];
                *(unsigned short*)(lds + 16384 + d1 * 512 +
                    (cb ^ (((d1 & 7) ^ (d1 >> 3)) << 4))) = (unsigned short)v1[e];
            }
        }
    }
    __syncthreads();

    f32x4 acc[4][2] = {};

    for (int kt = 0; kt < 4; ++kt) {
        #pragma unroll
        for (int kk = 0; kk < 2; ++kk) {
            bf16x8 af[4], bfr[2];
            #pragma unroll
            for (int mi = 0; mi < 4; ++mi) {
                const int row = wm + (mi << 4) + r16;
                af[mi] = *(const bf16x8*)(lds + row * 128 + ((((kk << 2) + g) ^ (row & 7)) << 4));
            }
            #pragma unroll
            for (int nj = 0; nj < 2; ++nj) {
                const int d = wn + (nj << 4) + r16;
                const int kbyte = (kt << 7) + ((((kk << 2) + g)) << 4);
                bfr[nj] = *(const bf16x8*)(lds + 16384 + d * 512 +
                    (kbyte ^ (((d & 7) ^ (d >> 3)) << 4)));
            }
            #pragma unroll
            for (int mi = 0; mi < 4; ++mi)
                #pragma unroll
                for (int nj = 0; nj < 2; ++nj)
                    acc[mi][nj] = __builtin_amdgcn_mfma_f32_16x16x32_bf16(af[mi], bfr[nj], acc[mi][nj], 0, 0, 0);
        }
        if (kt < 3) {
            __syncthreads();
            const int kc = (kt + 1) << 6;
            #pragma unroll
            for (int i = 0; i < 4; ++i) {
                const int row = (i << 5) + trow;
                const int gs  = slot ^ (row & 7);
                GLD_LDS((const char*)(Ab + (size_t)row * 256 + kc) + gs * 16,
                        lds + (i << 12) + tid * 16);
            }
            __syncthreads();
        }
    }

    const int b = bh >> 3, h = bh & 7;
    #pragma unroll
    for (int mi = 0; mi < 4; ++mi)
        #pragma unroll
        for (int nj = 0; nj < 2; ++nj)
            #pragma unroll
            for (int j = 0; j < 4; ++j) {
                const int row = m0 + wm + (mi << 4) + (g << 2) + j;
                const int col = n0 + wn + (nj << 4) + r16;
                Ao[((size_t)b * CC + row) * HWS + h * DD + col] = f2bf(acc[mi][nj][j]);
            }
}

extern "C" void kernel_launch(void* const* d_in, const int* in_sizes, int n_in,
                              void* d_out, int out_size, void* d_ws, size_t ws_size,
                              hipStream_t stream)
{
    const float* x  = (const float*)d_in[0];
    const float* qw = (const float*)d_in[1];
    const float* qb = (const float*)d_in[2];
    const float* kw = (const float*)d_in[3];
    const float* kb = (const float*)d_in[4];
    const float* vw = (const float*)d_in[5];
    const float* vb = (const float*)d_in[6];
    const float* ow = (const float*)d_in[7];
    const float* ob = (const float*)d_in[8];
    float* out = (float*)d_out;

    char* wsb = (char*)d_ws;
    __hip_bfloat16* q   = (__hip_bfloat16*)(wsb + 16777216UL);
    __hip_bfloat16* k   = (__hip_bfloat16*)(wsb + 50331648UL);
    float*          S   = (float*)(wsb + 83886080UL);
    __hip_bfloat16* P   = (__hip_bfloat16*)(wsb + 92274688UL);
    __hip_bfloat16* v   = (__hip_bfloat16*)(wsb + 96468992UL);
    unsigned short* A   = (unsigned short*)(wsb + 0);   // dead region by PV time
    // Toeplitz f16 tables alias S (6.9 MB <= 8 MB): consumed by conv9qkv before
    // gemm_qk writes S (stream-ordered).
    unsigned short* wt  = (unsigned short*)(wsb + 83886080UL);

    build_wt<<<dim3(CC, 3), 256, 0, stream>>>(qw, kw, vw, wt);
    conv9qkv<<<dim3(1024), 1024, 0, stream>>>(
        x, wt, qb, kb, vb,
        (unsigned short*)q, (unsigned short*)k, (unsigned short*)v);
    gemm_qk<<<dim3(4, 4, 32), 256, 0, stream>>>(
        (const unsigned short*)q, (const unsigned short*)k, S);
    softmax_kernel<<<dim3(2048), 256, 0, stream>>>(S, (unsigned short*)P);
    gemm_pv<<<dim3(32, 2, 32), 256, 0, stream>>>(
        (const unsigned short*)P, (const unsigned short*)v, A);
    conv9o<<<dim3(CC * 8), 512, 0, stream>>>(A, ow, ob, out);
}

// Round 16
// 163.281 us; speedup vs baseline: 1.7011x; 1.7011x over previous
//
#include <hip/hip_runtime.h>
#include <hip/hip_bf16.h>
#include <math.h>

#define BB 4
#define CC 256
#define HH 128
#define WW 128
#define HWS (HH*WW)          // 16384
#define NHEADS 8
#define DD (HWS/NHEADS)      // 2048

typedef __attribute__((ext_vector_type(8))) short bf16x8;
typedef __attribute__((ext_vector_type(4))) float f32x4;
typedef __attribute__((ext_vector_type(2))) __fp16 h16x2;
typedef __attribute__((ext_vector_type(8))) __fp16 h16x8;

#define GLD_LDS(g, l) __builtin_amdgcn_global_load_lds( \
    (const __attribute__((address_space(1))) void*)(g),  \
    (__attribute__((address_space(3))) void*)(l), 16, 0, 0)

static __device__ __forceinline__ unsigned short f2bf(float f) {
    unsigned int u = __float_as_uint(f);
    unsigned int r = (u + 0x7FFFu + ((u >> 16) & 1u)) >> 16;
    return (unsigned short)r;
}
static __device__ __forceinline__ float b2f(unsigned short u) {
    return __uint_as_float((unsigned int)u << 16);
}
static __device__ __forceinline__ unsigned int pk2(float a, float b) {
    union { h16x2 h; unsigned int u; } x;
    x.h = __builtin_amdgcn_cvt_pkrtz(a, b);
    return x.u;
}

// ---- Toeplitz fragment tables for MFMA conv: wt[c][cv][ky][lane][8] f16 ----
// T[m][k] = w[c][ky][k-m] for 0<=k-m<=8 else 0; lane: m=lane&15, k=(lane>>4)*8+e
__global__ __launch_bounds__(256) void build_wt(
    const float* __restrict__ qw, const float* __restrict__ kw,
    const float* __restrict__ vw, unsigned short* __restrict__ wt)
{
    const int c = blockIdx.x, cv = blockIdx.y;
    const float* w = (cv == 0) ? qw : (cv == 1) ? kw : vw;
    unsigned short* dst = wt + ((size_t)c * 3 + cv) * 9 * 512;
    for (int idx = threadIdx.x; idx < 9 * 512; idx += 256) {
        const int ky   = idx >> 9;
        const int rem  = idx & 511;
        const int lane = rem >> 3, e = rem & 7;
        const int m = lane & 15;
        const int k = ((lane >> 4) << 3) + e;
        const int d = k - m;
        const float v = (d >= 0 && d <= 8) ? w[c * 81 + ky * 9 + d] : 0.0f;
        const __fp16 hv = (__fp16)v;
        unsigned short bits;
        __builtin_memcpy(&bits, &hv, 2);
        dst[idx] = bits;
    }
}

// ------- fused QKV depthwise 9x9 conv — MFMA Toeplitz, 128x128 full-row tiles -------
// 1024 thr / 16 waves (8 wy x 2 wx); grid 1024 = 256c x 4batch (XCD-chunked).
// launch_bounds (1024,4): 128-VGPR cap. (1024,8)'s 64-cap spilled (r15: VGPR=32,
// WRITE 357MB) — same pathology as r10; body compiles ~40 under a >=85 cap (r12).
// LDS 66816 -> 2 blocks/CU = 32 waves (hardware cap).
#define FOFF 27648
#define PE_COEF   (-1.1243088e-3f) // -ln(10000)/8192
#define PE_RSTEP  (0.99887632f)    // exp(PE_COEF)
__global__ __launch_bounds__(1024, 4) void conv9qkv(
    const float* __restrict__ in,
    const unsigned short* __restrict__ wt,
    const float* __restrict__ b0, const float* __restrict__ b1,
    const float* __restrict__ b2,
    unsigned short* __restrict__ o0, unsigned short* __restrict__ o1,
    unsigned short* __restrict__ o2)
{
    __shared__ alignas(16) char lds[FOFF + 39168];   // 66816 B

    const int u    = ((blockIdx.x & 7) << 7) + (blockIdx.x >> 3);
    const int c    = u >> 2;
    const int bidx = u & 3;
    const int tid  = threadIdx.x;
    const int lane = tid & 63;
    const int wr   = tid >> 6;       // 0..15
    const int wy   = wr >> 1;        // 0..7
    const int wx   = wr & 1;         // 0..1
    const int r16  = lane & 15;
    const int g    = lane >> 4;

    // ---- async staging of the 27 Toeplitz fragments ----
    for (int f = wr; f < 27; f += 16) {
        const char* src = (const char*)wt + (((size_t)c * 27 + f) << 10) + (lane << 4);
        GLD_LDS(src, lds + (f << 10) + (lane << 4));
    }

    const float* xp = in + ((size_t)(bidx * CC + c) << 14);
    const float cf  = (float)c;

    // ---- stage 136x144 halo tile (x + inline PE) as f16, 288B stride, 8 px/item ----
    #pragma unroll
    for (int it = 0; it < 3; ++it) {
        const int i = tid + (it << 10);
        if (i < 2448) {
            const int row = i / 18;
            const int c8  = i - row * 18;
            const int gy  = row - 4;
            const int gx  = (c8 << 3) - 4;
            uint4 wv = make_uint4(0u, 0u, 0u, 0u);
            if (gy >= 0 && gy < HH) {
                const float* xr = xp + (gy << 7);
                if (gx >= 0 && gx + 7 < WW) {
                    const float4 a0 = *(const float4*)(xr + gx);
                    const float4 a1 = *(const float4*)(xr + gx + 4);
                    float dt = __expf(PE_COEF * (float)(((gy << 7) + gx) >> 1));
                    float s, cc;
                    __sincosf(cf * dt, &s, &cc);
                    wv.x = pk2(a0.x + s, a0.y + cc);
                    dt *= PE_RSTEP;
                    __sincosf(cf * dt, &s, &cc);
                    wv.y = pk2(a0.z + s, a0.w + cc);
                    dt *= PE_RSTEP;
                    __sincosf(cf * dt, &s, &cc);
                    wv.z = pk2(a1.x + s, a1.y + cc);
                    dt *= PE_RSTEP;
                    __sincosf(cf * dt, &s, &cc);
                    wv.w = pk2(a1.z + s, a1.w + cc);
                } else {
                    float vv[8];
                    #pragma unroll
                    for (int e = 0; e < 8; ++e) {
                        const int gxe = gx + e;
                        float xv = 0.f;
                        if (gxe >= 0 && gxe < WW) {
                            const int flat = (gy << 7) + gxe;
                            const float dt = __expf(PE_COEF * (float)(flat >> 1));
                            float s, cc;
                            __sincosf(cf * dt, &s, &cc);
                            xv = xr[gxe] + ((flat & 1) ? cc : s);
                        }
                        vv[e] = xv;
                    }
                    wv.x = pk2(vv[0], vv[1]); wv.y = pk2(vv[2], vv[3]);
                    wv.z = pk2(vv[4], vv[5]); wv.w = pk2(vv[6], vv[7]);
                }
            }
            int byte = row * 288 + (c8 << 4);
            byte ^= (row & 7) << 4;
            *(uint4*)(lds + FOFF + byte) = wv;
        }
    }
    __syncthreads();

    // ---- MFMA main: D[m=x][n=y] += T[m][k=x'] * In[k=x'][n=y], per ky ----
    f32x4 acc[3][4];
    {
        const float bq = b0[c], bk = b1[c], bv = b2[c];
        #pragma unroll
        for (int xt = 0; xt < 4; ++xt) {
            acc[0][xt] = (f32x4){bq, bq, bq, bq};
            acc[1][xt] = (f32x4){bk, bk, bk, bk};
            acc[2][xt] = (f32x4){bv, bv, bv, bv};
        }
    }

    const int rowbase = (wy << 4) + r16;     // output row 0..127
    const int xoff    = wx << 7;             // 0 or 128 bytes (64 cols)
    __builtin_amdgcn_s_setprio(1);
    for (int ky = 0; ky < 9; ++ky) {
        const int row = rowbase + ky;
        const int sx  = (row & 7) << 4;
        const int rb  = row * 288 + xoff + (g << 4);
        h16x8 a[4];
        #pragma unroll
        for (int xt = 0; xt < 4; ++xt)
            a[xt] = *(const h16x8*)(lds + FOFF + ((rb + (xt << 5)) ^ sx));
        #pragma unroll
        for (int cv = 0; cv < 3; ++cv) {
            const h16x8 tf = *(const h16x8*)(lds + ((cv * 9 + ky) << 10) + (lane << 4));
            #pragma unroll
            for (int xt = 0; xt < 4; ++xt)
                acc[cv][xt] = __builtin_amdgcn_mfma_f32_16x16x32_f16(
                    tf, a[xt], acc[cv][xt], 0, 0, 0);
        }
    }
    __builtin_amdgcn_s_setprio(0);

    // ---- epilogue: direct packed stores (lane holds 4 consecutive x at row y) ----
    unsigned short* const outs[3] = { o0, o1, o2 };
    const size_t base = (((size_t)(bidx * NHEADS + wy) * CC + c) << 11)
                      + ((size_t)r16 << 7) + (wx << 6) + (g << 2);
    #pragma unroll
    for (int cv = 0; cv < 3; ++cv)
        #pragma unroll
        for (int xt = 0; xt < 4; ++xt) {
            ushort4 uo;
            uo.x = f2bf(acc[cv][xt][0]); uo.y = f2bf(acc[cv][xt][1]);
            uo.z = f2bf(acc[cv][xt][2]); uo.w = f2bf(acc[cv][xt][3]);
            *(ushort4*)(outs[cv] + base + (xt << 4)) = uo;
        }
}

// ------- output depthwise 9x9 conv — 512-thr full-height tiles (byte-identical r12) -------
#define OTILE 21760
__global__ __launch_bounds__(512, 8) void conv9o(
    const unsigned short* __restrict__ ain,
    const float* __restrict__ w, const float* __restrict__ b,
    float* __restrict__ out)
{
    __shared__ alignas(16) char lds[OTILE + 9216];
    __shared__ float lw[81];

    const int u    = ((blockIdx.x & 7) << 8) + (blockIdx.x >> 3);
    const int c    = u >> 3;
    const int bidx = (u >> 1) & 3;
    const int tc   = (u & 1) << 6;
    const int plane = bidx * CC + c;
    const int tid  = threadIdx.x;
    const int lane = tid & 63;
    const int wr   = tid >> 6;
    const int r16  = lane & 15;
    const int g    = lane >> 4;

    if (tid < 81) lw[tid] = w[c * 81 + tid];

    const unsigned short* ap = ain + ((size_t)plane << 14);

    #pragma unroll
    for (int it = 0; it < 3; ++it) {
        const int i = tid + (it << 9);
        if (i < 1360) {
            const int row = i / 10;
            const int c8  = i - row * 10;
            const int gy  = row - 4;
            const int gx  = tc + (c8 << 3) - 4;
            uint4 wv = make_uint4(0u, 0u, 0u, 0u);
            if (gy >= 0 && gy < HH) {
                const unsigned short* ar = ap + (gy << 7);
                if (gx >= 0 && gx + 7 < WW) {
                    const bf16x8 uu = *(const bf16x8*)(ar + gx);
                    wv.x = pk2(b2f((unsigned short)uu[0]), b2f((unsigned short)uu[1]));
                    wv.y = pk2(b2f((unsigned short)uu[2]), b2f((unsigned short)uu[3]));
                    wv.z = pk2(b2f((unsigned short)uu[4]), b2f((unsigned short)uu[5]));
                    wv.w = pk2(b2f((unsigned short)uu[6]), b2f((unsigned short)uu[7]));
                } else {
                    float vv[8];
                    #pragma unroll
                    for (int e = 0; e < 8; ++e) {
                        const int gxe = gx + e;
                        vv[e] = (gxe >= 0 && gxe < WW) ? b2f(ar[gxe]) : 0.f;
                    }
                    wv.x = pk2(vv[0], vv[1]); wv.y = pk2(vv[2], vv[3]);
                    wv.z = pk2(vv[4], vv[5]); wv.w = pk2(vv[6], vv[7]);
                }
            }
            int byte = row * 160 + (c8 << 4);
            byte ^= (row & 7) << 4;
            *(uint4*)(lds + byte) = wv;
        }
    }
    __syncthreads();

    if (tid < 256) {
        const int ln = tid >> 2, qq = tid & 3;
        const int m  = ln & 15;
        const int k0 = ((ln >> 4) << 3) + (qq << 1);
        const int d0 = k0 - m, d1 = k0 + 1 - m;
        #pragma unroll
        for (int ky = 0; ky < 9; ++ky) {
            const float f0 = (d0 >= 0 && d0 <= 8) ? lw[ky * 9 + d0] : 0.f;
            const float f1 = (d1 >= 0 && d1 <= 8) ? lw[ky * 9 + d1] : 0.f;
            *(unsigned int*)(lds + OTILE + (ky << 10) + (ln << 4) + (qq << 2)) = pk2(f0, f1);
        }
    }
    __syncthreads();

    const float bv = b[c];
    f32x4 acc[4];
    #pragma unroll
    for (int xt = 0; xt < 4; ++xt) acc[xt] = (f32x4){bv, bv, bv, bv};

    const int rowbase = (wr << 4) + r16;
    __builtin_amdgcn_s_setprio(1);
    for (int ky = 0; ky < 9; ++ky) {
        const int row = rowbase + ky;
        const int sx  = (row & 7) << 4;
        const int rb  = row * 160 + (g << 4);
        h16x8 a[4];
        #pragma unroll
        for (int xt = 0; xt < 4; ++xt)
            a[xt] = *(const h16x8*)(lds + ((rb + (xt << 5)) ^ sx));
        const h16x8 tf = *(const h16x8*)(lds + OTILE + (ky << 10) + (lane << 4));
        #pragma unroll
        for (int xt = 0; xt < 4; ++xt)
            acc[xt] = __builtin_amdgcn_mfma_f32_16x16x32_f16(tf, a[xt], acc[xt], 0, 0, 0);
    }
    __builtin_amdgcn_s_setprio(0);

    const int y = (wr << 4) + r16;
    float* orow = out + ((size_t)plane << 14) + ((size_t)y << 7) + tc + (g << 2);
    #pragma unroll
    for (int xt = 0; xt < 4; ++xt)
        *(f32x4*)(orow + (xt << 4)) = acc[xt];
}

// ------------- bf16 MFMA GEMM for QK^T — double-buffered, 64x64 tiles (r12) -------------
__global__ __launch_bounds__(256) void gemm_qk(
    const unsigned short* __restrict__ Abuf, const unsigned short* __restrict__ Bbuf,
    float* __restrict__ Sout)
{
    constexpr int KT = 2048;

    __shared__ char lds[32768];   // two halves of 16KB: A 8KB + B 8KB each

    const int tid = threadIdx.x;
    const int bh  = blockIdx.z;
    const int m0  = blockIdx.y << 6;
    const int n0  = blockIdx.x << 6;

    const unsigned short* Ab = Abuf + (size_t)bh * CC * KT + (size_t)m0 * KT;
    const unsigned short* Bb = Bbuf + (size_t)bh * CC * KT + (size_t)n0 * KT;

    const int lane = tid & 63;
    const int w    = tid >> 6;       // 4 waves: 2m x 2n
    const int wm   = (w >> 1) << 5;
    const int wn   = (w & 1) << 5;
    const int r16  = lane & 15;
    const int g    = lane >> 4;

    const int trow = tid >> 3;       // 0..31
    const int slot = tid & 7;

    f32x4 acc[2][2] = {};

    auto stage = [&](int h, int kt) {
        const int kc = kt << 6;
        char* base = lds + h * 16384;
        #pragma unroll
        for (int i = 0; i < 2; ++i) {
            const int row = (i << 5) + trow;
            const int gs  = slot ^ (row & 7);
            GLD_LDS((const char*)(Ab + (size_t)row * KT + kc) + gs * 16,
                    base + (i << 12) + tid * 16);
        }
        #pragma unroll
        for (int i = 0; i < 2; ++i) {
            const int row = (i << 5) + trow;
            const int gs  = slot ^ (row & 7);
            GLD_LDS((const char*)(Bb + (size_t)row * KT + kc) + gs * 16,
                    base + 8192 + (i << 12) + tid * 16);
        }
    };

    stage(0, 0);
    __syncthreads();

    for (int kt = 0; kt < KT / 64; ++kt) {
        const int cur = kt & 1;
        if (kt + 1 < KT / 64) stage(cur ^ 1, kt + 1);
        const char* hb = lds + cur * 16384;
        #pragma unroll
        for (int kk = 0; kk < 2; ++kk) {
            bf16x8 af[2], bfr[2];
            #pragma unroll
            for (int mi = 0; mi < 2; ++mi) {
                const int row = wm + (mi << 4) + r16;
                af[mi] = *(const bf16x8*)(hb + row * 128 + ((((kk << 2) + g) ^ (row & 7)) << 4));
            }
            #pragma unroll
            for (int nj = 0; nj < 2; ++nj) {
                const int row = wn + (nj << 4) + r16;
                bfr[nj] = *(const bf16x8*)(hb + 8192 + row * 128 + ((((kk << 2) + g) ^ (row & 7)) << 4));
            }
            #pragma unroll
            for (int mi = 0; mi < 2; ++mi)
                #pragma unroll
                for (int nj = 0; nj < 2; ++nj)
                    acc[mi][nj] = __builtin_amdgcn_mfma_f32_16x16x32_bf16(af[mi], bfr[nj], acc[mi][nj], 0, 0, 0);
        }
        __syncthreads();
    }

    float* sp = Sout + (size_t)bh * 65536;
    #pragma unroll
    for (int mi = 0; mi < 2; ++mi)
        #pragma unroll
        for (int nj = 0; nj < 2; ++nj)
            #pragma unroll
            for (int j = 0; j < 4; ++j) {
                const int row = m0 + wm + (mi << 4) + (g << 2) + j;
                const int col = n0 + wn + (nj << 4) + r16;
                sp[(size_t)row * 256 + col] = acc[mi][nj][j] * 0.0078125f;
            }
}

// ------------- row softmax, wave-per-row (byte-identical r8) -------------
__global__ __launch_bounds__(256) void softmax_kernel(
    const float* __restrict__ S, unsigned short* __restrict__ P)
{
    const int row  = (blockIdx.x << 2) + (threadIdx.x >> 6);
    const int lane = threadIdx.x & 63;
    const float4 vv = *(const float4*)(S + ((size_t)row << 8) + (lane << 2));
    float m = fmaxf(fmaxf(vv.x, vv.y), fmaxf(vv.z, vv.w));
    #pragma unroll
    for (int o = 32; o; o >>= 1) m = fmaxf(m, __shfl_xor(m, o, 64));
    const float e0 = __expf(vv.x - m), e1 = __expf(vv.y - m);
    const float e2 = __expf(vv.z - m), e3 = __expf(vv.w - m);
    float s = (e0 + e1) + (e2 + e3);
    #pragma unroll
    for (int o = 32; o; o >>= 1) s += __shfl_xor(s, o, 64);
    const float r = 1.0f / s;
    ushort4 u;
    u.x = f2bf(e0 * r); u.y = f2bf(e1 * r); u.z = f2bf(e2 * r); u.w = f2bf(e3 * r);
    *(ushort4*)(P + ((size_t)row << 8) + (lane << 2)) = u;
}

// ------------- PV GEMM with fused V-transpose (byte-identical r12, 128-row tiles) -------------
__global__ __launch_bounds__(256) void gemm_pv(
    const unsigned short* __restrict__ Pbuf, const unsigned short* __restrict__ vbuf,
    unsigned short* __restrict__ Ao)
{
    __shared__ alignas(16) char lds[49152];

    const int tid = threadIdx.x;
    const int bh  = blockIdx.z;
    const int m0  = blockIdx.y << 7;
    const int n0  = blockIdx.x << 6;

    const unsigned short* Ab = Pbuf + ((size_t)bh << 16) + ((size_t)m0 << 8);

    const int lane = tid & 63;
    const int w    = tid >> 6;
    const int wm   = (w >> 1) << 6;
    const int wn   = (w & 1) << 5;
    const int r16  = lane & 15;
    const int g    = lane >> 4;
    const int trow = tid >> 3;
    const int slot = tid & 7;

    {
        #pragma unroll
        for (int i = 0; i < 4; ++i) {
            const int row = (i << 5) + trow;
            const int gs  = slot ^ (row & 7);
            GLD_LDS((const char*)(Ab + (size_t)row * 256) + gs * 16,
                    lds + (i << 12) + tid * 16);
        }
    }

    {
        const unsigned short* Vb = vbuf + (size_t)bh * (CC * DD) + n0;
        const int rl = tid >> 2, q4 = tid & 3;
        #pragma unroll
        for (int p = 0; p < 4; ++p) {
            const int cp = (p << 6) + rl;
            const unsigned short* src = Vb + (size_t)cp * DD + (q4 << 4);
            const bf16x8 v0 = *(const bf16x8*)(src);
            const bf16x8 v1 = *(const bf16x8*)(src + 8);
            const int cb = cp << 1;
            #pragma unroll
            for (int e = 0; e < 8; ++e) {
                const int d0 = (q4 << 4) + e, d1 = d0 + 8;
                *(unsigned short*)(lds + 16384 + d0 * 512 +
                    (cb ^ (((d0 & 7) ^ (d0 >> 3)) << 4))) = (unsigned short)v0[e];
                *(unsigned short*)(lds + 16384 + d1 * 512 +
                    (cb ^ (((d1 & 7) ^ (d1 >> 3)) << 4))) = (unsigned short)v1[e];
            }
        }
    }
    __syncthreads();

    f32x4 acc[4][2] = {};

    for (int kt = 0; kt < 4; ++kt) {
        #pragma unroll
        for (int kk = 0; kk < 2; ++kk) {
            bf16x8 af[4], bfr[2];
            #pragma unroll
            for (int mi = 0; mi < 4; ++mi) {
                const int row = wm + (mi << 4) + r16;
                af[mi] = *(const bf16x8*)(lds + row * 128 + ((((kk << 2) + g) ^ (row & 7)) << 4));
            }
            #pragma unroll
            for (int nj = 0; nj < 2; ++nj) {
                const int d = wn + (nj << 4) + r16;
                const int kbyte = (kt << 7) + ((((kk << 2) + g)) << 4);
                bfr[nj] = *(const bf16x8*)(lds + 16384 + d * 512 +
                    (kbyte ^ (((d & 7) ^ (d >> 3)) << 4)));
            }
            #pragma unroll
            for (int mi = 0; mi < 4; ++mi)
                #pragma unroll
                for (int nj = 0; nj < 2; ++nj)
                    acc[mi][nj] = __builtin_amdgcn_mfma_f32_16x16x32_bf16(af[mi], bfr[nj], acc[mi][nj], 0, 0, 0);
        }
        if (kt < 3) {
            __syncthreads();
            const int kc = (kt + 1) << 6;
            #pragma unroll
            for (int i = 0; i < 4; ++i) {
                const int row = (i << 5) + trow;
                const int gs  = slot ^ (row & 7);
                GLD_LDS((const char*)(Ab + (size_t)row * 256 + kc) + gs * 16,
                        lds + (i << 12) + tid * 16);
            }
            __syncthreads();
        }
    }

    const int b = bh >> 3, h = bh & 7;
    #pragma unroll
    for (int mi = 0; mi < 4; ++mi)
        #pragma unroll
        for (int nj = 0; nj < 2; ++nj)
            #pragma unroll
            for (int j = 0; j < 4; ++j) {
                const int row = m0 + wm + (mi << 4) + (g << 2) + j;
                const int col = n0 + wn + (nj << 4) + r16;
                Ao[((size_t)b * CC + row) * HWS + h * DD + col] = f2bf(acc[mi][nj][j]);
            }
}

extern "C" void kernel_launch(void* const* d_in, const int* in_sizes, int n_in,
                              void* d_out, int out_size, void* d_ws, size_t ws_size,
                              hipStream_t stream)
{
    const float* x  = (const float*)d_in[0];
    const float* qw = (const float*)d_in[1];
    const float* qb = (const float*)d_in[2];
    const float* kw = (const float*)d_in[3];
    const float* kb = (const float*)d_in[4];
    const float* vw = (const float*)d_in[5];
    const float* vb = (const float*)d_in[6];
    const float* ow = (const float*)d_in[7];
    const float* ob = (const float*)d_in[8];
    float* out = (float*)d_out;

    char* wsb = (char*)d_ws;
    __hip_bfloat16* q   = (__hip_bfloat16*)(wsb + 16777216UL);
    __hip_bfloat16* k   = (__hip_bfloat16*)(wsb + 50331648UL);
    float*          S   = (float*)(wsb + 83886080UL);
    __hip_bfloat16* P   = (__hip_bfloat16*)(wsb + 92274688UL);
    __hip_bfloat16* v   = (__hip_bfloat16*)(wsb + 96468992UL);
    unsigned short* A   = (unsigned short*)(wsb + 0);   // dead region by PV time
    // Toeplitz f16 tables alias S (6.9 MB <= 8 MB): consumed by conv9qkv before
    // gemm_qk writes S (stream-ordered).
    unsigned short* wt  = (unsigned short*)(wsb + 83886080UL);

    build_wt<<<dim3(CC, 3), 256, 0, stream>>>(qw, kw, vw, wt);
    conv9qkv<<<dim3(1024), 1024, 0, stream>>>(
        x, wt, qb, kb, vb,
        (unsigned short*)q, (unsigned short*)k, (unsigned short*)v);
    gemm_qk<<<dim3(4, 4, 32), 256, 0, stream>>>(
        (const unsigned short*)q, (const unsigned short*)k, S);
    softmax_kernel<<<dim3(2048), 256, 0, stream>>>(S, (unsigned short*)P);
    gemm_pv<<<dim3(32, 2, 32), 256, 0, stream>>>(
        (const unsigned short*)P, (const unsigned short*)v, A);
    conv9o<<<dim3(CC * 8), 512, 0, stream>>>(A, ow, ob, out);
}

// Round 17
// 140.980 us; speedup vs baseline: 1.9702x; 1.1582x over previous
//
#include <hip/hip_runtime.h>
#include <hip/hip_bf16.h>
#include <math.h>

#define BB 4
#define CC 256
#define HH 128
#define WW 128
#define HWS (HH*WW)          // 16384
#define NHEADS 8
#define DD (HWS/NHEADS)      // 2048

typedef __attribute__((ext_vector_type(8))) short bf16x8;
typedef __attribute__((ext_vector_type(4))) float f32x4;
typedef __attribute__((ext_vector_type(2))) __fp16 h16x2;
typedef __attribute__((ext_vector_type(8))) __fp16 h16x8;

#define GLD_LDS(g, l) __builtin_amdgcn_global_load_lds( \
    (const __attribute__((address_space(1))) void*)(g),  \
    (__attribute__((address_space(3))) void*)(l), 16, 0, 0)

static __device__ __forceinline__ unsigned short f2bf(float f) {
    unsigned int u = __float_as_uint(f);
    unsigned int r = (u + 0x7FFFu + ((u >> 16) & 1u)) >> 16;
    return (unsigned short)r;
}
static __device__ __forceinline__ float b2f(unsigned short u) {
    return __uint_as_float((unsigned int)u << 16);
}
static __device__ __forceinline__ unsigned int pk2(float a, float b) {
    union { h16x2 h; unsigned int u; } x;
    x.h = __builtin_amdgcn_cvt_pkrtz(a, b);
    return x.u;
}

// ---- Toeplitz fragment tables for MFMA conv: wt[c][cv][ky][lane][8] f16 ----
// T[m][k] = w[c][ky][k-m] for 0<=k-m<=8 else 0; lane: m=lane&15, k=(lane>>4)*8+e
__global__ __launch_bounds__(256) void build_wt(
    const float* __restrict__ qw, const float* __restrict__ kw,
    const float* __restrict__ vw, unsigned short* __restrict__ wt)
{
    const int c = blockIdx.x, cv = blockIdx.y;
    const float* w = (cv == 0) ? qw : (cv == 1) ? kw : vw;
    unsigned short* dst = wt + ((size_t)c * 3 + cv) * 9 * 512;
    for (int idx = threadIdx.x; idx < 9 * 512; idx += 256) {
        const int ky   = idx >> 9;
        const int rem  = idx & 511;
        const int lane = rem >> 3, e = rem & 7;
        const int m = lane & 15;
        const int k = ((lane >> 4) << 3) + e;
        const int d = k - m;
        const float v = (d >= 0 && d <= 8) ? w[c * 81 + ky * 9 + d] : 0.0f;
        const __fp16 hv = (__fp16)v;
        unsigned short bits;
        __builtin_memcpy(&bits, &hv, 2);
        dst[idx] = bits;
    }
}

// ------- fused QKV depthwise 9x9 conv — MFMA Toeplitz, 512-thr full-height tiles -------
// (the measured optimum: 128x64 tiles, 8 waves, 3 blocks/CU. Tile-geometry map:
// 64x64=91us, 128x64=75us, 128x128=103us, batch-looped=138us. LDS-diet/compressed
// variants spill ~100-400MB scratch — axes closed r9-r16.)
#define FOFF 27648
#define PE_COEF   (-1.1243088e-3f) // -ln(10000)/8192
#define PE_RSTEP  (0.99887632f)    // exp(PE_COEF)
__global__ __launch_bounds__(512, 6) void conv9qkv(
    const float* __restrict__ in,
    const unsigned short* __restrict__ wt,
    const float* __restrict__ b0, const float* __restrict__ b1,
    const float* __restrict__ b2,
    unsigned short* __restrict__ o0, unsigned short* __restrict__ o1,
    unsigned short* __restrict__ o2)
{
    __shared__ alignas(16) char lds[FOFF + 21760];   // 49408 B

    const int u    = ((blockIdx.x & 7) << 8) + (blockIdx.x >> 3);
    const int c    = u >> 3;
    const int bidx = (u >> 1) & 3;
    const int tc   = (u & 1) << 6;
    const int tid  = threadIdx.x;
    const int lane = tid & 63;
    const int wr   = tid >> 6;       // 0..7
    const int r16  = lane & 15;
    const int g    = lane >> 4;

    for (int f = wr; f < 27; f += 8) {
        const char* src = (const char*)wt + (((size_t)c * 27 + f) << 10) + (lane << 4);
        GLD_LDS(src, lds + (f << 10) + (lane << 4));
    }

    const float* xp = in + ((size_t)(bidx * CC + c) << 14);
    const float cf  = (float)c;

    #pragma unroll
    for (int it = 0; it < 3; ++it) {
        const int i = tid + (it << 9);
        if (i < 1360) {
            const int row = i / 10;
            const int c8  = i - row * 10;
            const int gy  = row - 4;
            const int gx  = tc + (c8 << 3) - 4;
            uint4 wv = make_uint4(0u, 0u, 0u, 0u);
            if (gy >= 0 && gy < HH) {
                const float* xr = xp + (gy << 7);
                if (gx >= 0 && gx + 7 < WW) {
                    const float4 a0 = *(const float4*)(xr + gx);
                    const float4 a1 = *(const float4*)(xr + gx + 4);
                    float dt = __expf(PE_COEF * (float)(((gy << 7) + gx) >> 1));
                    float s, cc;
                    __sincosf(cf * dt, &s, &cc);
                    wv.x = pk2(a0.x + s, a0.y + cc);
                    dt *= PE_RSTEP;
                    __sincosf(cf * dt, &s, &cc);
                    wv.y = pk2(a0.z + s, a0.w + cc);
                    dt *= PE_RSTEP;
                    __sincosf(cf * dt, &s, &cc);
                    wv.z = pk2(a1.x + s, a1.y + cc);
                    dt *= PE_RSTEP;
                    __sincosf(cf * dt, &s, &cc);
                    wv.w = pk2(a1.z + s, a1.w + cc);
                } else {
                    float vv[8];
                    #pragma unroll
                    for (int e = 0; e < 8; ++e) {
                        const int gxe = gx + e;
                        float xv = 0.f;
                        if (gxe >= 0 && gxe < WW) {
                            const int flat = (gy << 7) + gxe;
                            const float dt = __expf(PE_COEF * (float)(flat >> 1));
                            float s, cc;
                            __sincosf(cf * dt, &s, &cc);
                            xv = xr[gxe] + ((flat & 1) ? cc : s);
                        }
                        vv[e] = xv;
                    }
                    wv.x = pk2(vv[0], vv[1]); wv.y = pk2(vv[2], vv[3]);
                    wv.z = pk2(vv[4], vv[5]); wv.w = pk2(vv[6], vv[7]);
                }
            }
            int byte = row * 160 + (c8 << 4);
            byte ^= (row & 7) << 4;
            *(uint4*)(lds + FOFF + byte) = wv;
        }
    }
    __syncthreads();

    f32x4 acc[3][4];
    {
        const float bq = b0[c], bk = b1[c], bv = b2[c];
        #pragma unroll
        for (int xt = 0; xt < 4; ++xt) {
            acc[0][xt] = (f32x4){bq, bq, bq, bq};
            acc[1][xt] = (f32x4){bk, bk, bk, bk};
            acc[2][xt] = (f32x4){bv, bv, bv, bv};
        }
    }

    const int rowbase = (wr << 4) + r16;     // output row 0..127
    __builtin_amdgcn_s_setprio(1);
    for (int ky = 0; ky < 9; ++ky) {
        const int row = rowbase + ky;
        const int sx  = (row & 7) << 4;
        const int rb  = row * 160 + (g << 4);
        h16x8 a[4];
        #pragma unroll
        for (int xt = 0; xt < 4; ++xt)
            a[xt] = *(const h16x8*)(lds + FOFF + ((rb + (xt << 5)) ^ sx));
        #pragma unroll
        for (int cv = 0; cv < 3; ++cv) {
            const h16x8 tf = *(const h16x8*)(lds + ((cv * 9 + ky) << 10) + (lane << 4));
            #pragma unroll
            for (int xt = 0; xt < 4; ++xt)
                acc[cv][xt] = __builtin_amdgcn_mfma_f32_16x16x32_f16(
                    tf, a[xt], acc[cv][xt], 0, 0, 0);
        }
    }
    __builtin_amdgcn_s_setprio(0);

    unsigned short* const outs[3] = { o0, o1, o2 };
    const size_t base = (((size_t)(bidx * NHEADS + wr) * CC + c) << 11)
                      + ((size_t)r16 << 7) + tc + (g << 2);
    #pragma unroll
    for (int cv = 0; cv < 3; ++cv)
        #pragma unroll
        for (int xt = 0; xt < 4; ++xt) {
            ushort4 uo;
            uo.x = f2bf(acc[cv][xt][0]); uo.y = f2bf(acc[cv][xt][1]);
            uo.z = f2bf(acc[cv][xt][2]); uo.w = f2bf(acc[cv][xt][3]);
            *(ushort4*)(outs[cv] + base + (xt << 4)) = uo;
        }
}

// ------- output depthwise 9x9 conv — 512-thr full-height tiles (byte-identical r12) -------
#define OTILE 21760
__global__ __launch_bounds__(512, 8) void conv9o(
    const unsigned short* __restrict__ ain,
    const float* __restrict__ w, const float* __restrict__ b,
    float* __restrict__ out)
{
    __shared__ alignas(16) char lds[OTILE + 9216];
    __shared__ float lw[81];

    const int u    = ((blockIdx.x & 7) << 8) + (blockIdx.x >> 3);
    const int c    = u >> 3;
    const int bidx = (u >> 1) & 3;
    const int tc   = (u & 1) << 6;
    const int plane = bidx * CC + c;
    const int tid  = threadIdx.x;
    const int lane = tid & 63;
    const int wr   = tid >> 6;
    const int r16  = lane & 15;
    const int g    = lane >> 4;

    if (tid < 81) lw[tid] = w[c * 81 + tid];

    const unsigned short* ap = ain + ((size_t)plane << 14);

    #pragma unroll
    for (int it = 0; it < 3; ++it) {
        const int i = tid + (it << 9);
        if (i < 1360) {
            const int row = i / 10;
            const int c8  = i - row * 10;
            const int gy  = row - 4;
            const int gx  = tc + (c8 << 3) - 4;
            uint4 wv = make_uint4(0u, 0u, 0u, 0u);
            if (gy >= 0 && gy < HH) {
                const unsigned short* ar = ap + (gy << 7);
                if (gx >= 0 && gx + 7 < WW) {
                    const bf16x8 uu = *(const bf16x8*)(ar + gx);
                    wv.x = pk2(b2f((unsigned short)uu[0]), b2f((unsigned short)uu[1]));
                    wv.y = pk2(b2f((unsigned short)uu[2]), b2f((unsigned short)uu[3]));
                    wv.z = pk2(b2f((unsigned short)uu[4]), b2f((unsigned short)uu[5]));
                    wv.w = pk2(b2f((unsigned short)uu[6]), b2f((unsigned short)uu[7]));
                } else {
                    float vv[8];
                    #pragma unroll
                    for (int e = 0; e < 8; ++e) {
                        const int gxe = gx + e;
                        vv[e] = (gxe >= 0 && gxe < WW) ? b2f(ar[gxe]) : 0.f;
                    }
                    wv.x = pk2(vv[0], vv[1]); wv.y = pk2(vv[2], vv[3]);
                    wv.z = pk2(vv[4], vv[5]); wv.w = pk2(vv[6], vv[7]);
                }
            }
            int byte = row * 160 + (c8 << 4);
            byte ^= (row & 7) << 4;
            *(uint4*)(lds + byte) = wv;
        }
    }
    __syncthreads();

    if (tid < 256) {
        const int ln = tid >> 2, qq = tid & 3;
        const int m  = ln & 15;
        const int k0 = ((ln >> 4) << 3) + (qq << 1);
        const int d0 = k0 - m, d1 = k0 + 1 - m;
        #pragma unroll
        for (int ky = 0; ky < 9; ++ky) {
            const float f0 = (d0 >= 0 && d0 <= 8) ? lw[ky * 9 + d0] : 0.f;
            const float f1 = (d1 >= 0 && d1 <= 8) ? lw[ky * 9 + d1] : 0.f;
            *(unsigned int*)(lds + OTILE + (ky << 10) + (ln << 4) + (qq << 2)) = pk2(f0, f1);
        }
    }
    __syncthreads();

    const float bv = b[c];
    f32x4 acc[4];
    #pragma unroll
    for (int xt = 0; xt < 4; ++xt) acc[xt] = (f32x4){bv, bv, bv, bv};

    const int rowbase = (wr << 4) + r16;
    __builtin_amdgcn_s_setprio(1);
    for (int ky = 0; ky < 9; ++ky) {
        const int row = rowbase + ky;
        const int sx  = (row & 7) << 4;
        const int rb  = row * 160 + (g << 4);
        h16x8 a[4];
        #pragma unroll
        for (int xt = 0; xt < 4; ++xt)
            a[xt] = *(const h16x8*)(lds + ((rb + (xt << 5)) ^ sx));
        const h16x8 tf = *(const h16x8*)(lds + OTILE + (ky << 10) + (lane << 4));
        #pragma unroll
        for (int xt = 0; xt < 4; ++xt)
            acc[xt] = __builtin_amdgcn_mfma_f32_16x16x32_f16(tf, a[xt], acc[xt], 0, 0, 0);
    }
    __builtin_amdgcn_s_setprio(0);

    const int y = (wr << 4) + r16;
    float* orow = out + ((size_t)plane << 14) + ((size_t)y << 7) + tc + (g << 2);
    #pragma unroll
    for (int xt = 0; xt < 4; ++xt)
        *(f32x4*)(orow + (xt << 4)) = acc[xt];
}

// ------------- bf16 MFMA GEMM for QK^T — double-buffered, 64x64 tiles (r12) -------------
__global__ __launch_bounds__(256) void gemm_qk(
    const unsigned short* __restrict__ Abuf, const unsigned short* __restrict__ Bbuf,
    float* __restrict__ Sout)
{
    constexpr int KT = 2048;

    __shared__ char lds[32768];   // two halves of 16KB: A 8KB + B 8KB each

    const int tid = threadIdx.x;
    const int bh  = blockIdx.z;
    const int m0  = blockIdx.y << 6;
    const int n0  = blockIdx.x << 6;

    const unsigned short* Ab = Abuf + (size_t)bh * CC * KT + (size_t)m0 * KT;
    const unsigned short* Bb = Bbuf + (size_t)bh * CC * KT + (size_t)n0 * KT;

    const int lane = tid & 63;
    const int w    = tid >> 6;       // 4 waves: 2m x 2n
    const int wm   = (w >> 1) << 5;
    const int wn   = (w & 1) << 5;
    const int r16  = lane & 15;
    const int g    = lane >> 4;

    const int trow = tid >> 3;       // 0..31
    const int slot = tid & 7;

    f32x4 acc[2][2] = {};

    auto stage = [&](int h, int kt) {
        const int kc = kt << 6;
        char* base = lds + h * 16384;
        #pragma unroll
        for (int i = 0; i < 2; ++i) {
            const int row = (i << 5) + trow;
            const int gs  = slot ^ (row & 7);
            GLD_LDS((const char*)(Ab + (size_t)row * KT + kc) + gs * 16,
                    base + (i << 12) + tid * 16);
        }
        #pragma unroll
        for (int i = 0; i < 2; ++i) {
            const int row = (i << 5) + trow;
            const int gs  = slot ^ (row & 7);
            GLD_LDS((const char*)(Bb + (size_t)row * KT + kc) + gs * 16,
                    base + 8192 + (i << 12) + tid * 16);
        }
    };

    stage(0, 0);
    __syncthreads();

    for (int kt = 0; kt < KT / 64; ++kt) {
        const int cur = kt & 1;
        if (kt + 1 < KT / 64) stage(cur ^ 1, kt + 1);
        const char* hb = lds + cur * 16384;
        #pragma unroll
        for (int kk = 0; kk < 2; ++kk) {
            bf16x8 af[2], bfr[2];
            #pragma unroll
            for (int mi = 0; mi < 2; ++mi) {
                const int row = wm + (mi << 4) + r16;
                af[mi] = *(const bf16x8*)(hb + row * 128 + ((((kk << 2) + g) ^ (row & 7)) << 4));
            }
            #pragma unroll
            for (int nj = 0; nj < 2; ++nj) {
                const int row = wn + (nj << 4) + r16;
                bfr[nj] = *(const bf16x8*)(hb + 8192 + row * 128 + ((((kk << 2) + g) ^ (row & 7)) << 4));
            }
            #pragma unroll
            for (int mi = 0; mi < 2; ++mi)
                #pragma unroll
                for (int nj = 0; nj < 2; ++nj)
                    acc[mi][nj] = __builtin_amdgcn_mfma_f32_16x16x32_bf16(af[mi], bfr[nj], acc[mi][nj], 0, 0, 0);
        }
        __syncthreads();
    }

    float* sp = Sout + (size_t)bh * 65536;
    #pragma unroll
    for (int mi = 0; mi < 2; ++mi)
        #pragma unroll
        for (int nj = 0; nj < 2; ++nj)
            #pragma unroll
            for (int j = 0; j < 4; ++j) {
                const int row = m0 + wm + (mi << 4) + (g << 2) + j;
                const int col = n0 + wn + (nj << 4) + r16;
                sp[(size_t)row * 256 + col] = acc[mi][nj][j] * 0.0078125f;
            }
}

// ------------- row softmax, wave-per-row (byte-identical r8) -------------
__global__ __launch_bounds__(256) void softmax_kernel(
    const float* __restrict__ S, unsigned short* __restrict__ P)
{
    const int row  = (blockIdx.x << 2) + (threadIdx.x >> 6);
    const int lane = threadIdx.x & 63;
    const float4 vv = *(const float4*)(S + ((size_t)row << 8) + (lane << 2));
    float m = fmaxf(fmaxf(vv.x, vv.y), fmaxf(vv.z, vv.w));
    #pragma unroll
    for (int o = 32; o; o >>= 1) m = fmaxf(m, __shfl_xor(m, o, 64));
    const float e0 = __expf(vv.x - m), e1 = __expf(vv.y - m);
    const float e2 = __expf(vv.z - m), e3 = __expf(vv.w - m);
    float s = (e0 + e1) + (e2 + e3);
    #pragma unroll
    for (int o = 32; o; o >>= 1) s += __shfl_xor(s, o, 64);
    const float r = 1.0f / s;
    ushort4 u;
    u.x = f2bf(e0 * r); u.y = f2bf(e1 * r); u.z = f2bf(e2 * r); u.w = f2bf(e3 * r);
    *(ushort4*)(P + ((size_t)row << 8) + (lane << 2)) = u;
}

// ------------- PV GEMM with fused V-transpose (byte-identical r12, 128-row tiles) -------------
__global__ __launch_bounds__(256) void gemm_pv(
    const unsigned short* __restrict__ Pbuf, const unsigned short* __restrict__ vbuf,
    unsigned short* __restrict__ Ao)
{
    __shared__ alignas(16) char lds[49152];

    const int tid = threadIdx.x;
    const int bh  = blockIdx.z;
    const int m0  = blockIdx.y << 7;
    const int n0  = blockIdx.x << 6;

    const unsigned short* Ab = Pbuf + ((size_t)bh << 16) + ((size_t)m0 << 8);

    const int lane = tid & 63;
    const int w    = tid >> 6;
    const int wm   = (w >> 1) << 6;
    const int wn   = (w & 1) << 5;
    const int r16  = lane & 15;
    const int g    = lane >> 4;
    const int trow = tid >> 3;
    const int slot = tid & 7;

    {
        #pragma unroll
        for (int i = 0; i < 4; ++i) {
            const int row = (i << 5) + trow;
            const int gs  = slot ^ (row & 7);
            GLD_LDS((const char*)(Ab + (size_t)row * 256) + gs * 16,
                    lds + (i << 12) + tid * 16);
        }
    }

    {
        const unsigned short* Vb = vbuf + (size_t)bh * (CC * DD) + n0;
        const int rl = tid >> 2, q4 = tid & 3;
        #pragma unroll
        for (int p = 0; p < 4; ++p) {
            const int cp = (p << 6) + rl;
            const unsigned short* src = Vb + (size_t)cp * DD + (q4 << 4);
            const bf16x8 v0 = *(const bf16x8*)(src);
            const bf16x8 v1 = *(const bf16x8*)(src + 8);
            const int cb = cp << 1;
            #pragma unroll
            for (int e = 0; e < 8; ++e) {
                const int d0 = (q4 << 4) + e, d1 = d0 + 8;
                *(unsigned short*)(lds + 16384 + d0 * 512 +
                    (cb ^ (((d0 & 7) ^ (d0 >> 3)) << 4))) = (unsigned short)v0[e];
                *(unsigned short*)(lds + 16384 + d1 * 512 +
                    (cb ^ (((d1 & 7) ^ (d1 >> 3)) << 4))) = (unsigned short)v1[e];
            }
        }
    }
    __syncthreads();

    f32x4 acc[4][2] = {};

    for (int kt = 0; kt < 4; ++kt) {
        #pragma unroll
        for (int kk = 0; kk < 2; ++kk) {
            bf16x8 af[4], bfr[2];
            #pragma unroll
            for (int mi = 0; mi < 4; ++mi) {
                const int row = wm + (mi << 4) + r16;
                af[mi] = *(const bf16x8*)(lds + row * 128 + ((((kk << 2) + g) ^ (row & 7)) << 4));
            }
            #pragma unroll
            for (int nj = 0; nj < 2; ++nj) {
                const int d = wn + (nj << 4) + r16;
                const int kbyte = (kt << 7) + ((((kk << 2) + g)) << 4);
                bfr[nj] = *(const bf16x8*)(lds + 16384 + d * 512 +
                    (kbyte ^ (((d & 7) ^ (d >> 3)) << 4)));
            }
            #pragma unroll
            for (int mi = 0; mi < 4; ++mi)
                #pragma unroll
                for (int nj = 0; nj < 2; ++nj)
                    acc[mi][nj] = __builtin_amdgcn_mfma_f32_16x16x32_bf16(af[mi], bfr[nj], acc[mi][nj], 0, 0, 0);
        }
        if (kt < 3) {
            __syncthreads();
            const int kc = (kt + 1) << 6;
            #pragma unroll
            for (int i = 0; i < 4; ++i) {
                const int row = (i << 5) + trow;
                const int gs  = slot ^ (row & 7);
                GLD_LDS((const char*)(Ab + (size_t)row * 256 + kc) + gs * 16,
                        lds + (i << 12) + tid * 16);
            }
            __syncthreads();
        }
    }

    const int b = bh >> 3, h = bh & 7;
    #pragma unroll
    for (int mi = 0; mi < 4; ++mi)
        #pragma unroll
        for (int nj = 0; nj < 2; ++nj)
            #pragma unroll
            for (int j = 0; j < 4; ++j) {
                const int row = m0 + wm + (mi << 4) + (g << 2) + j;
                const int col = n0 + wn + (nj << 4) + r16;
                Ao[((size_t)b * CC + row) * HWS + h * DD + col] = f2bf(acc[mi][nj][j]);
            }
}

extern "C" void kernel_launch(void* const* d_in, const int* in_sizes, int n_in,
                              void* d_out, int out_size, void* d_ws, size_t ws_size,
                              hipStream_t stream)
{
    const float* x  = (const float*)d_in[0];
    const float* qw = (const float*)d_in[1];
    const float* qb = (const float*)d_in[2];
    const float* kw = (const float*)d_in[3];
    const float* kb = (const float*)d_in[4];
    const float* vw = (const float*)d_in[5];
    const float* vb = (const float*)d_in[6];
    const float* ow = (const float*)d_in[7];
    const float* ob = (const float*)d_in[8];
    float* out = (float*)d_out;

    char* wsb = (char*)d_ws;
    __hip_bfloat16* q   = (__hip_bfloat16*)(wsb + 16777216UL);
    __hip_bfloat16* k   = (__hip_bfloat16*)(wsb + 50331648UL);
    float*          S   = (float*)(wsb + 83886080UL);
    __hip_bfloat16* P   = (__hip_bfloat16*)(wsb + 92274688UL);
    __hip_bfloat16* v   = (__hip_bfloat16*)(wsb + 96468992UL);
    unsigned short* A   = (unsigned short*)(wsb + 0);   // dead region by PV time
    // Toeplitz f16 tables alias S (6.9 MB <= 8 MB): consumed by conv9qkv before
    // gemm_qk writes S (stream-ordered).
    unsigned short* wt  = (unsigned short*)(wsb + 83886080UL);

    build_wt<<<dim3(CC, 3), 256, 0, stream>>>(qw, kw, vw, wt);
    conv9qkv<<<dim3(CC * 8), 512, 0, stream>>>(
        x, wt, qb, kb, vb,
        (unsigned short*)q, (unsigned short*)k, (unsigned short*)v);
    gemm_qk<<<dim3(4, 4, 32), 256, 0, stream>>>(
        (const unsigned short*)q, (const unsigned short*)k, S);
    softmax_kernel<<<dim3(2048), 256, 0, stream>>>(S, (unsigned short*)P);
    gemm_pv<<<dim3(32, 2, 32), 256, 0, stream>>>(
        (const unsigned short*)P, (const unsigned short*)v, A);
    conv9o<<<dim3(CC * 8), 512, 0, stream>>>(A, ow, ob, out);
}